// Round 3
// baseline (3612.128 us; speedup 1.0000x reference)
//
#include <hip/hip_runtime.h>
#include <hip/hip_bf16.h>

typedef __bf16 bf16;
typedef __attribute__((ext_vector_type(8))) __bf16 bf16x8;
typedef __attribute__((ext_vector_type(4))) float f32x4;

#define MFMA16(a, b, c) __builtin_amdgcn_mfma_f32_16x16x32_bf16((a), (b), (c), 0, 0, 0)

// ---------------------------------------------------------------------------
// GEMM: C[M,N] = A[M,K] @ W[K,N] + bias, W pre-transposed+quantized as WT[N,K]
// (bf16). A is bf16; bias is fp32. MODE 0: bf16 out; MODE 1: fp32 out;
// MODE 2: gelu(exact) + bf16 out.
// Tiles: BM=BN=128, BK=32; 256 threads = 4 waves in 2x2; wave does 64x64.
// ---------------------------------------------------------------------------
template <int MODE>
__global__ __launch_bounds__(256) void gemm_kernel(
    const bf16* __restrict__ A, const bf16* __restrict__ WT,
    const float* __restrict__ b0, const float* __restrict__ b1, const float* __restrict__ b2,
    int s1, int s2, void* __restrict__ outp, int M, int N, int K)
{
    __shared__ __align__(16) bf16 sA[128 * 32];
    __shared__ __align__(16) bf16 sB[128 * 32];

    const int tid  = threadIdx.x;
    const int lane = tid & 63;
    const int wave = tid >> 6;
    const int quad = lane >> 4;
    const int l15  = lane & 15;
    const int wm   = (wave >> 1) * 64;
    const int wn   = (wave & 1) * 64;
    const int bm   = blockIdx.y * 128;
    const int bn   = blockIdx.x * 128;

    f32x4 acc[4][4];
#pragma unroll
    for (int i = 0; i < 4; i++)
#pragma unroll
        for (int j = 0; j < 4; j++)
#pragma unroll
            for (int r = 0; r < 4; r++) acc[i][j][r] = 0.0f;

    // staging chunk ids: 512 chunks of 16B per 8KB tile, 2 per thread
    const int idx0 = tid;
    const int idx1 = tid + 256;
    const int ra0 = idx0 >> 2, ca0 = (idx0 & 3) * 8;
    const int ra1 = idx1 >> 2, ca1 = (idx1 & 3) * 8;

    const int nk = K >> 5;
    for (int kt = 0; kt < nk; kt++) {
        const int k0 = kt * 32;
        const uint4 a0 = *(const uint4*)(A  + (size_t)(bm + ra0) * K + k0 + ca0);
        const uint4 a1 = *(const uint4*)(A  + (size_t)(bm + ra1) * K + k0 + ca1);
        const uint4 w0 = *(const uint4*)(WT + (size_t)(bn + ra0) * K + k0 + ca0);
        const uint4 w1 = *(const uint4*)(WT + (size_t)(bn + ra1) * K + k0 + ca1);
        __syncthreads();   // prior iteration's LDS reads complete
        *(uint4*)(sA + idx0 * 8) = a0;
        *(uint4*)(sA + idx1 * 8) = a1;
        *(uint4*)(sB + idx0 * 8) = w0;
        *(uint4*)(sB + idx1 * 8) = w1;
        __syncthreads();   // stores visible

        bf16x8 af[4], bf_[4];
#pragma unroll
        for (int i = 0; i < 4; i++)
            af[i] = *(const bf16x8*)(sA + (wm + i * 16 + l15) * 32 + quad * 8);
#pragma unroll
        for (int i = 0; i < 4; i++)
            bf_[i] = *(const bf16x8*)(sB + (wn + i * 16 + l15) * 32 + quad * 8);
#pragma unroll
        for (int mt = 0; mt < 4; mt++)
#pragma unroll
            for (int nt = 0; nt < 4; nt++)
                acc[mt][nt] = MFMA16(af[mt], bf_[nt], acc[mt][nt]);
    }

    // epilogue: C/D layout col = lane&15, row = quad*4 + r  (m89/m91 verified)
#pragma unroll
    for (int nt = 0; nt < 4; nt++) {
        const int col = bn + wn + nt * 16 + l15;
        const float bias = (col < s1) ? b0[col]
                         : (col < s2) ? b1[col - s1]
                                      : b2[col - s2];
#pragma unroll
        for (int mt = 0; mt < 4; mt++) {
#pragma unroll
            for (int r = 0; r < 4; r++) {
                const int row = bm + wm + mt * 16 + quad * 4 + r;
                float v = acc[mt][nt][r] + bias;
                if (MODE == 2) v = 0.5f * v * (1.0f + erff(v * 0.70710678118654752f));
                if (MODE == 1) ((float*)outp)[(size_t)row * N + col] = v;
                else           ((bf16*)outp)[(size_t)row * N + col] = (bf16)v;
            }
        }
    }
}

// ---------------------------------------------------------------------------
// Attention: one block = (b, h, 32-row Q tile). 128 threads = 2 waves.
// QKV packed bf16 [4096, 2304] (Q|K|V). Scores (bf16) in LDS; full softmax;
// PV with V transposed in LDS so both MFMA fragments are ds_read_b128.
// ---------------------------------------------------------------------------
__global__ __launch_bounds__(128) void attn_kernel(
    const bf16* __restrict__ qkv, const float* __restrict__ mask, bf16* __restrict__ ctx)
{
    const int b = blockIdx.z, h = blockIdx.y, q0 = blockIdx.x * 32;
    const int tid = threadIdx.x, lane = tid & 63, wave = tid >> 6;
    const int quad = lane >> 4, l15 = lane & 15;

    __shared__ __align__(16) bf16 sQ[32 * 64];
    __shared__ __align__(16) bf16 sKV[64 * 64];
    __shared__ __align__(16) bf16 sS[32 * 512];
    __shared__ float sAM[512];
    __shared__ float sRed[32 * 4];
    __shared__ float sRow[32];

    for (int i = tid; i < 512; i += 128)
        sAM[i] = (1.0f - mask[b * 512 + i]) * -10000.0f;

    const size_t RS = 2304;
    const bf16* Qb = qkv + (size_t)(b * 512 + q0) * RS + h * 64;
#pragma unroll
    for (int i = 0; i < 2; i++) {
        int idx = i * 128 + tid;
        int r = idx >> 3, c = (idx & 7) * 8;
        *(uint4*)(sQ + r * 64 + c) = *(const uint4*)(Qb + (size_t)r * RS + c);
    }

    // ---- phase B: S = Q @ K^T (raw scores, bf16 in LDS) ----
#pragma unroll 1
    for (int kt = 0; kt < 8; kt++) {
        __syncthreads();
        const bf16* Kb = qkv + (size_t)(b * 512 + kt * 64) * RS + 768 + h * 64;
#pragma unroll
        for (int i = 0; i < 4; i++) {
            int idx = i * 128 + tid;
            int r = idx >> 3, c = (idx & 7) * 8;
            *(uint4*)(sKV + r * 64 + c) = *(const uint4*)(Kb + (size_t)r * RS + c);
        }
        __syncthreads();
        bf16x8 aQ0 = *(const bf16x8*)(sQ + (wave * 16 + l15) * 64 + quad * 8);
        bf16x8 aQ1 = *(const bf16x8*)(sQ + (wave * 16 + l15) * 64 + 32 + quad * 8);
#pragma unroll
        for (int nt = 0; nt < 4; nt++) {
            f32x4 accS;
#pragma unroll
            for (int r = 0; r < 4; r++) accS[r] = 0.0f;
            accS = MFMA16(aQ0, *(const bf16x8*)(sKV + (nt * 16 + l15) * 64 + quad * 8), accS);
            accS = MFMA16(aQ1, *(const bf16x8*)(sKV + (nt * 16 + l15) * 64 + 32 + quad * 8), accS);
#pragma unroll
            for (int r = 0; r < 4; r++) {
                const int row = wave * 16 + quad * 4 + r;
                sS[row * 512 + kt * 64 + nt * 16 + l15] = (bf16)accS[r];
            }
        }
    }
    __syncthreads();

    // ---- phase C: softmax over the 512 keys (scale + mask fused) ----
    {
        const int r = tid >> 2, p = tid & 3;
        bf16* srow = sS + r * 512 + p * 128;
        const float* am = sAM + p * 128;
        float mx = -1e30f;
        for (int j = 0; j < 128; j++) {
            float v = (float)srow[j] * 0.125f + am[j];
            mx = fmaxf(mx, v);
        }
        sRed[r * 4 + p] = mx;
        __syncthreads();
        mx = fmaxf(fmaxf(sRed[r * 4], sRed[r * 4 + 1]), fmaxf(sRed[r * 4 + 2], sRed[r * 4 + 3]));
        __syncthreads();
        float sum = 0.0f;
        for (int j = 0; j < 128; j++) {
            float v = (float)srow[j] * 0.125f + am[j];
            float e = __expf(v - mx);
            sum += e;
            srow[j] = (bf16)e;
        }
        sRed[r * 4 + p] = sum;
        __syncthreads();
        if (p == 0) sRow[r] = sRed[r * 4] + sRed[r * 4 + 1] + sRed[r * 4 + 2] + sRed[r * 4 + 3];
    }

    // ---- phase D: O = P @ V ----
    f32x4 accO[4];
#pragma unroll
    for (int i = 0; i < 4; i++)
#pragma unroll
        for (int r = 0; r < 4; r++) accO[i][r] = 0.0f;

#pragma unroll 1
    for (int kt = 0; kt < 8; kt++) {
        __syncthreads();
        const bf16* Vb = qkv + (size_t)(b * 512 + kt * 64) * RS + 1536 + h * 64;
#pragma unroll
        for (int i = 0; i < 4; i++) {
            int idx = i * 128 + tid;
            int j = idx >> 3, c = (idx & 7) * 8;
            uint4 raw = *(const uint4*)(Vb + (size_t)j * RS + c);
            const bf16* t = (const bf16*)&raw;
#pragma unroll
            for (int e = 0; e < 8; e++) sKV[(c + e) * 64 + j] = t[e];  // V^T: [dim][key]
        }
        __syncthreads();
#pragma unroll
        for (int kk = 0; kk < 2; kk++) {
            bf16x8 aP = *(const bf16x8*)(sS + (wave * 16 + l15) * 512 + kt * 64 + kk * 32 + quad * 8);
#pragma unroll
            for (int nt = 0; nt < 4; nt++) {
                bf16x8 bV = *(const bf16x8*)(sKV + (nt * 16 + l15) * 64 + kk * 32 + quad * 8);
                accO[nt] = MFMA16(aP, bV, accO[nt]);
            }
        }
    }
#pragma unroll
    for (int nt = 0; nt < 4; nt++) {
#pragma unroll
        for (int r = 0; r < 4; r++) {
            const int row = wave * 16 + quad * 4 + r;
            const float o = accO[nt][r] / sRow[row];
            ctx[(size_t)(b * 512 + q0 + row) * 768 + h * 64 + nt * 16 + l15] = (bf16)o;
        }
    }
}

// ---------------------------------------------------------------------------
// Fused residual-add + LayerNorm. One block (256 thr) per row of 768.
// y fp32 (GEMM out), resid fp32, gamma/beta fp32.
// Writes bf16 (next GEMM input) and fp32 (next residual / final output).
// ---------------------------------------------------------------------------
__global__ __launch_bounds__(256) void ln_kernel(
    const float* __restrict__ y, const float* __restrict__ resid,
    const float* __restrict__ g, const float* __restrict__ bb,
    bf16* __restrict__ out_bf, float* __restrict__ out_f32)
{
    const int row = blockIdx.x;
    const int tid = threadIdx.x;
    __shared__ float sS[4], sQ[4];

    float x[3], s = 0.0f, sq = 0.0f;
#pragma unroll
    for (int j = 0; j < 3; j++) {
        const int c = tid + j * 256;
        const float v = y[(size_t)row * 768 + c] + resid[(size_t)row * 768 + c];
        x[j] = v; s += v; sq += v * v;
    }
#pragma unroll
    for (int off = 32; off; off >>= 1) { s += __shfl_down(s, off); sq += __shfl_down(sq, off); }
    if ((tid & 63) == 0) { sS[tid >> 6] = s; sQ[tid >> 6] = sq; }
    __syncthreads();
    s  = sS[0] + sS[1] + sS[2] + sS[3];
    sq = sQ[0] + sQ[1] + sQ[2] + sQ[3];
    const float mean = s * (1.0f / 768.0f);
    float var = sq * (1.0f / 768.0f) - mean * mean;
    var = fmaxf(var, 0.0f);
    const float rstd = rsqrtf(var + 1e-12f);
#pragma unroll
    for (int j = 0; j < 3; j++) {
        const int c = tid + j * 256;
        const float v = (x[j] - mean) * rstd * g[c] + bb[c];
        out_bf[(size_t)row * 768 + c] = (bf16)v;
        out_f32[(size_t)row * 768 + c] = v;
    }
}

// ---------------------------------------------------------------------------
// Transpose + quantize all 6 fp32 weight matrices of one layer into bf16 wT:
//   WqT@0, WkT@589824, WvT@1179648, WaoT@1769472, WiT@2359296, WoT@4718592
// ---------------------------------------------------------------------------
__global__ __launch_bounds__(256) void transpose_kernel(
    const float* __restrict__ Wq, const float* __restrict__ Wk, const float* __restrict__ Wv,
    const float* __restrict__ Wao, const float* __restrict__ Wi, const float* __restrict__ Wo,
    bf16* __restrict__ wT)
{
    __shared__ bf16 tile[64 * 68];
    int id = blockIdx.x;
    const float* src; bf16* dst; int Kd, Nd;
    if (id < 576) {
        const int w = id / 144; id -= w * 144;
        Kd = 768; Nd = 768;
        src = (w == 0) ? Wq : (w == 1) ? Wk : (w == 2) ? Wv : Wao;
        dst = wT + (size_t)w * 589824;
    } else if (id < 1152) {
        id -= 576; Kd = 768; Nd = 3072; src = Wi; dst = wT + 2359296;
    } else {
        id -= 1152; Kd = 3072; Nd = 768; src = Wo; dst = wT + 4718592;
    }
    const int tn = Nd >> 6;
    const int tr = id / tn, tc = id - tr * tn;
    const int r0 = tr * 64, c0 = tc * 64;
    const int tid = threadIdx.x;

#pragma unroll
    for (int i = 0; i < 4; i++) {
        const int idx = i * 256 + tid;
        const int r = idx >> 4, c4 = (idx & 15) * 4;
        const float4 f = *(const float4*)(src + (size_t)(r0 + r) * Nd + c0 + c4);
        alignas(8) bf16 q[4] = {(bf16)f.x, (bf16)f.y, (bf16)f.z, (bf16)f.w};
        *(ushort4*)(tile + r * 68 + c4) = *(ushort4*)q;
    }
    __syncthreads();
#pragma unroll
    for (int i = 0; i < 4; i++) {
        const int idx = i * 256 + tid;
        const int n = idx >> 4, kc = (idx & 15) * 4;
        alignas(8) bf16 tmp[4];
#pragma unroll
        for (int e = 0; e < 4; e++) tmp[e] = tile[(kc + e) * 68 + n];
        *(ushort4*)(dst + (size_t)(c0 + n) * Kd + r0 + kc) = *(ushort4*)tmp;
    }
}

// fp32 -> bf16 cast (hidden_states -> GEMM A input)
__global__ __launch_bounds__(256) void convert_kernel(
    const float* __restrict__ in, bf16* __restrict__ out, int n)
{
    const int i = blockIdx.x * 256 + threadIdx.x;
    if (i < n) out[i] = (bf16)in[i];
}

// ---------------------------------------------------------------------------
extern "C" void kernel_launch(void* const* d_in, const int* in_sizes, int n_in,
                              void* d_out, int out_size, void* d_ws, size_t ws_size,
                              hipStream_t stream)
{
    // All reference tensors are float32.
    const float* hidden = (const float*)d_in[0];
    const float* mask   = (const float*)d_in[1];
    const float* Wq  = (const float*)d_in[2];  const float* bq  = (const float*)d_in[3];
    const float* Wk  = (const float*)d_in[4];  const float* bk  = (const float*)d_in[5];
    const float* Wv  = (const float*)d_in[6];  const float* bv  = (const float*)d_in[7];
    const float* Wao = (const float*)d_in[8];  const float* bao = (const float*)d_in[9];
    const float* g1  = (const float*)d_in[10]; const float* be1 = (const float*)d_in[11];
    const float* Wi  = (const float*)d_in[12]; const float* bi  = (const float*)d_in[13];
    const float* Wo  = (const float*)d_in[14]; const float* bo  = (const float*)d_in[15];
    const float* g2  = (const float*)d_in[16]; const float* be2 = (const float*)d_in[17];

    // workspace layout (aliased, total ~89.7 MB):
    char* ws = (char*)d_ws;
    bf16*  wT    = (bf16*)(ws);                    // [0, 14155776)
    bf16*  qkv   = (bf16*)(ws + 14155776);         // [14155776, 33030144)
    bf16*  ctx   = (bf16*)(ws + 33030144);         // [33030144, 39321600)
    bf16*  ffh   = (bf16*)(ws + 14155776);         // aliases qkv+ctx (both dead by FF1)
    float* g32   = (float*)(ws + 39321600);        // [39321600, 51904512)
    float* xf    = (float*)(ws + 51904512);        // [51904512, 64487424)
    bf16*  attnb = (bf16*)(ws + 64487424);         // [64487424, 70778880)
    float* attnf = (float*)(ws + 70778880);        // [70778880, 83361792)
    bf16*  xb    = (bf16*)(ws + 83361792);         // [83361792, 89653248)

    // hidden (fp32) -> bf16 GEMM input for layer 0
    convert_kernel<<<12288, 256, 0, stream>>>(hidden, xb, 3145728);

    for (int l = 0; l < 12; l++) {
        transpose_kernel<<<1728, 256, 0, stream>>>(
            Wq + (size_t)l * 589824, Wk + (size_t)l * 589824, Wv + (size_t)l * 589824,
            Wao + (size_t)l * 589824, Wi + (size_t)l * 2359296, Wo + (size_t)l * 2359296, wT);

        // QKV fused: N = 2304 (bias select per 768-segment)
        gemm_kernel<0><<<dim3(18, 32), 256, 0, stream>>>(
            xb, wT, bq + l * 768, bk + l * 768, bv + l * 768, 768, 1536,
            qkv, 4096, 2304, 768);

        attn_kernel<<<dim3(16, 12, 8), 128, 0, stream>>>(qkv, mask, ctx);

        gemm_kernel<1><<<dim3(6, 32), 256, 0, stream>>>(
            ctx, wT + 1769472, bao + l * 768, bao + l * 768, bao + l * 768, 768, 768,
            g32, 4096, 768, 768);

        // residual for LN1 is the layer input: hidden (fp32) at l=0, else xf
        const float* resid1 = (l == 0) ? hidden : xf;
        ln_kernel<<<4096, 256, 0, stream>>>(g32, resid1, g1 + l * 768, be1 + l * 768, attnb, attnf);

        gemm_kernel<2><<<dim3(24, 32), 256, 0, stream>>>(
            attnb, wT + 2359296, bi + l * 3072, bi + l * 3072, bi + l * 3072, 3072, 3072,
            ffh, 4096, 3072, 768);

        gemm_kernel<1><<<dim3(6, 32), 256, 0, stream>>>(
            ffh, wT + 4718592, bo + l * 768, bo + l * 768, bo + l * 768, 768, 768,
            g32, 4096, 768, 3072);

        // LN2: bf16 -> xb (next layer's GEMM input), fp32 -> xf (next residual)
        // last layer: fp32 result goes straight to d_out
        float* f32dst = (l == 11) ? (float*)d_out : xf;
        ln_kernel<<<4096, 256, 0, stream>>>(g32, attnf, g2 + l * 768, be2 + l * 768, xb, f32dst);
    }
}

// Round 4
// 3000.030 us; speedup vs baseline: 1.2040x; 1.2040x over previous
//
#include <hip/hip_runtime.h>
#include <hip/hip_bf16.h>

typedef __bf16 bf16;
typedef __attribute__((ext_vector_type(8))) __bf16 bf16x8;
typedef __attribute__((ext_vector_type(4))) float f32x4;

#define MFMA16(a, b, c) __builtin_amdgcn_mfma_f32_16x16x32_bf16((a), (b), (c), 0, 0, 0)

__device__ __forceinline__ void async16(const bf16* g, bf16* l) {
    __builtin_amdgcn_global_load_lds((__attribute__((address_space(1))) void*)(g),
                                     (__attribute__((address_space(3))) void*)(l), 16, 0, 0);
}

// ---------------------------------------------------------------------------
// GEMM: C[M,N] = A[M,K] @ W[K,N] + bias, W pre-transposed+quantized as WT[N,K]
// (bf16). MODE 0: bf16 out; MODE 1: fp32 out; MODE 2: gelu(exact) + bf16 out.
// BM=BN=128, BK=32; 256 thr = 4 waves 2x2; global_load_lds width-16 staging.
// ---------------------------------------------------------------------------
template <int MODE>
__global__ __launch_bounds__(256) void gemm_kernel(
    const bf16* __restrict__ A, const bf16* __restrict__ WT,
    const float* __restrict__ b0, const float* __restrict__ b1, const float* __restrict__ b2,
    int s1, int s2, void* __restrict__ outp, int M, int N, int K)
{
    __shared__ __align__(16) bf16 sA[128 * 32];
    __shared__ __align__(16) bf16 sB[128 * 32];

    const int tid  = threadIdx.x;
    const int lane = tid & 63;
    const int wave = tid >> 6;
    const int quad = lane >> 4;
    const int l15  = lane & 15;
    const int wm   = (wave >> 1) * 64;
    const int wn   = (wave & 1) * 64;
    const int bm   = blockIdx.y * 128;
    const int bn   = blockIdx.x * 128;

    f32x4 acc[4][4];
#pragma unroll
    for (int i = 0; i < 4; i++)
#pragma unroll
        for (int j = 0; j < 4; j++)
#pragma unroll
            for (int r = 0; r < 4; r++) acc[i][j][r] = 0.0f;

    const int idx0 = tid;
    const int idx1 = tid + 256;
    const int ra0 = idx0 >> 2, ca0 = (idx0 & 3) * 8;
    const int ra1 = idx1 >> 2, ca1 = (idx1 & 3) * 8;

    const int nk = K >> 5;
    for (int kt = 0; kt < nk; kt++) {
        const int k0 = kt * 32;
        __syncthreads();   // prior iteration's LDS reads complete
        async16(A  + (size_t)(bm + ra0) * K + k0 + ca0, sA + idx0 * 8);
        async16(A  + (size_t)(bm + ra1) * K + k0 + ca1, sA + idx1 * 8);
        async16(WT + (size_t)(bn + ra0) * K + k0 + ca0, sB + idx0 * 8);
        async16(WT + (size_t)(bn + ra1) * K + k0 + ca1, sB + idx1 * 8);
        __syncthreads();   // vmcnt drained at barrier -> tiles visible

        bf16x8 af[4], bf_[4];
#pragma unroll
        for (int i = 0; i < 4; i++)
            af[i] = *(const bf16x8*)(sA + (wm + i * 16 + l15) * 32 + quad * 8);
#pragma unroll
        for (int i = 0; i < 4; i++)
            bf_[i] = *(const bf16x8*)(sB + (wn + i * 16 + l15) * 32 + quad * 8);
#pragma unroll
        for (int mt = 0; mt < 4; mt++)
#pragma unroll
            for (int nt = 0; nt < 4; nt++)
                acc[mt][nt] = MFMA16(af[mt], bf_[nt], acc[mt][nt]);
    }

    // epilogue: C/D layout col = lane&15, row = quad*4 + r
#pragma unroll
    for (int nt = 0; nt < 4; nt++) {
        const int col = bn + wn + nt * 16 + l15;
        const float bias = (col < s1) ? b0[col]
                         : (col < s2) ? b1[col - s1]
                                      : b2[col - s2];
#pragma unroll
        for (int mt = 0; mt < 4; mt++) {
#pragma unroll
            for (int r = 0; r < 4; r++) {
                const int row = bm + wm + mt * 16 + quad * 4 + r;
                float v = acc[mt][nt][r] + bias;
                if (MODE == 2) v = 0.5f * v * (1.0f + erff(v * 0.70710678118654752f));
                if (MODE == 1) ((float*)outp)[(size_t)row * N + col] = v;
                else           ((bf16*)outp)[(size_t)row * N + col] = (bf16)v;
            }
        }
    }
}

// ---------------------------------------------------------------------------
// V-transpose: qkv V-part [key][dim] -> vT[bh][dim][key], coalesced both ways.
// grid: (4 keytiles of 128, 96 bh). LDS pad 72 (144B rows, 16B-aligned).
// ---------------------------------------------------------------------------
__global__ __launch_bounds__(256) void vtrans_kernel(
    const bf16* __restrict__ qkv, bf16* __restrict__ vT)
{
    const int bh = blockIdx.y;           // b*12 + h
    const int b = bh / 12, h = bh - b * 12;
    const int k0 = blockIdx.x * 128;
    __shared__ __align__(16) bf16 tile[128 * 72];
    const int tid = threadIdx.x;
    const bf16* src = qkv + (size_t)(b * 512 + k0) * 2304 + 1536 + h * 64;
#pragma unroll
    for (int i = 0; i < 4; i++) {
        const int idx = i * 256 + tid;
        const int r = idx >> 3, c = (idx & 7) * 8;      // key r, dim c
        *(uint4*)(tile + r * 72 + c) = *(const uint4*)(src + (size_t)r * 2304 + c);
    }
    __syncthreads();
    bf16* dst = vT + (size_t)bh * 64 * 512 + k0;
#pragma unroll
    for (int i = 0; i < 4; i++) {
        const int idx = i * 256 + tid;
        const int d = idx & 63, kg = idx >> 6;          // dim d, key-group kg
        alignas(16) bf16 tmp[8];
#pragma unroll
        for (int e = 0; e < 8; e++) tmp[e] = tile[(kg * 8 + e) * 72 + d];
        *(uint4*)(dst + (size_t)d * 512 + kg * 8) = *(uint4*)tmp;
    }
}

// ---------------------------------------------------------------------------
// Attention: one block = (b, h, 32-row Q tile), 256 threads = 4 waves.
// S kept in LDS (stride 520); vectorized conflict-free softmax; PV reads V
// from pre-transposed vT (no in-kernel scatter).
// ---------------------------------------------------------------------------
__global__ __launch_bounds__(256) void attn_kernel(
    const bf16* __restrict__ qkv, const bf16* __restrict__ vT,
    const float* __restrict__ mask, bf16* __restrict__ ctx)
{
    const int b = blockIdx.z, h = blockIdx.y, q0 = blockIdx.x * 32;
    const int bh = b * 12 + h;
    const int tid = threadIdx.x, lane = tid & 63, wave = tid >> 6;
    const int quad = lane >> 4, l15 = lane & 15;
    const int mt = wave & 1;             // row half (0..1)
    const int whi = wave >> 1;           // col half (0..1)

    __shared__ __align__(16) bf16 sQ[32 * 80];
    __shared__ __align__(16) bf16 sKV[64 * 80];
    __shared__ __align__(16) bf16 sS[32 * 520];
    __shared__ float sAM[512];
    __shared__ float sRedM[32 * 8];
    __shared__ float sRedS[32 * 8];
    __shared__ float sRow[32];

    for (int i = tid; i < 512; i += 256)
        sAM[i] = (1.0f - mask[b * 512 + i]) * -10000.0f;

    const size_t RS = 2304;
    // stage Q tile: 32 rows x 64 dims, one uint4 per thread
    {
        const int r = tid >> 3, c = (tid & 7) * 8;
        *(uint4*)(sQ + r * 80 + c) =
            *(const uint4*)(qkv + (size_t)(b * 512 + q0 + r) * RS + h * 64 + c);
    }

    // ---- phase B: S = Q @ K^T ----
#pragma unroll 1
    for (int kt = 0; kt < 8; kt++) {
        __syncthreads();
        const bf16* Kb = qkv + (size_t)(b * 512 + kt * 64) * RS + 768 + h * 64;
#pragma unroll
        for (int i = 0; i < 2; i++) {
            const int idx = i * 256 + tid;
            const int r = idx >> 3, c = (idx & 7) * 8;
            *(uint4*)(sKV + r * 80 + c) = *(const uint4*)(Kb + (size_t)r * RS + c);
        }
        __syncthreads();
        bf16x8 aQ0 = *(const bf16x8*)(sQ + (mt * 16 + l15) * 80 + quad * 8);
        bf16x8 aQ1 = *(const bf16x8*)(sQ + (mt * 16 + l15) * 80 + 32 + quad * 8);
#pragma unroll
        for (int n = 0; n < 2; n++) {
            const int nt = whi * 2 + n;
            f32x4 accS;
#pragma unroll
            for (int r = 0; r < 4; r++) accS[r] = 0.0f;
            accS = MFMA16(aQ0, *(const bf16x8*)(sKV + (nt * 16 + l15) * 80 + quad * 8), accS);
            accS = MFMA16(aQ1, *(const bf16x8*)(sKV + (nt * 16 + l15) * 80 + 32 + quad * 8), accS);
#pragma unroll
            for (int r = 0; r < 4; r++) {
                const int row = mt * 16 + quad * 4 + r;
                sS[row * 520 + kt * 64 + nt * 16 + l15] = (bf16)accS[r];
            }
        }
    }
    __syncthreads();

    // ---- phase C: softmax (vectorized, interleaved chunks: conflict-free) ----
    {
        const int r = tid >> 3, p = tid & 7;    // row 0..31, chunk 0..7
        float mx = -1e30f;
#pragma unroll
        for (int t = 0; t < 8; t++) {
            const int v0 = (p + 8 * t) * 8;
            bf16x8 pv = *(const bf16x8*)(sS + r * 520 + v0);
#pragma unroll
            for (int e = 0; e < 8; e++)
                mx = fmaxf(mx, (float)pv[e] * 0.125f + sAM[v0 + e]);
        }
        sRedM[r * 8 + p] = mx;
        __syncthreads();
#pragma unroll
        for (int q = 0; q < 8; q++) mx = fmaxf(mx, sRedM[r * 8 + q]);
        float sum = 0.0f;
#pragma unroll
        for (int t = 0; t < 8; t++) {
            const int v0 = (p + 8 * t) * 8;
            bf16x8 pv = *(const bf16x8*)(sS + r * 520 + v0);
            bf16x8 ev;
#pragma unroll
            for (int e = 0; e < 8; e++) {
                const float x = __expf((float)pv[e] * 0.125f + sAM[v0 + e] - mx);
                sum += x;
                ev[e] = (bf16)x;
            }
            *(bf16x8*)(sS + r * 520 + v0) = ev;
        }
        sRedS[r * 8 + p] = sum;
        __syncthreads();
        if (p == 0) {
            float s = 0.0f;
#pragma unroll
            for (int q = 0; q < 8; q++) s += sRedS[r * 8 + q];
            sRow[r] = s;
        }
    }

    // ---- phase D: O = P @ V (V from vT, coalesced staging) ----
    f32x4 accO[2];
#pragma unroll
    for (int i = 0; i < 2; i++)
#pragma unroll
        for (int r = 0; r < 4; r++) accO[i][r] = 0.0f;

#pragma unroll 1
    for (int kt = 0; kt < 8; kt++) {
        __syncthreads();
        const bf16* Vt = vT + (size_t)bh * 64 * 512 + kt * 64;
#pragma unroll
        for (int i = 0; i < 2; i++) {
            const int idx = i * 256 + tid;
            const int r = idx >> 3, c = (idx & 7) * 8;  // dim r, key c
            *(uint4*)(sKV + r * 80 + c) = *(const uint4*)(Vt + (size_t)r * 512 + c);
        }
        __syncthreads();
#pragma unroll
        for (int kk = 0; kk < 2; kk++) {
            bf16x8 aP = *(const bf16x8*)(sS + (mt * 16 + l15) * 520 + kt * 64 + kk * 32 + quad * 8);
#pragma unroll
            for (int n = 0; n < 2; n++) {
                bf16x8 bV = *(const bf16x8*)(sKV + (whi * 32 + n * 16 + l15) * 80 + kk * 32 + quad * 8);
                accO[n] = MFMA16(aP, bV, accO[n]);
            }
        }
    }
#pragma unroll
    for (int n = 0; n < 2; n++) {
#pragma unroll
        for (int r = 0; r < 4; r++) {
            const int row = mt * 16 + quad * 4 + r;
            const float o = accO[n][r] / sRow[row];
            ctx[(size_t)(b * 512 + q0 + row) * 768 + h * 64 + whi * 32 + n * 16 + l15] = (bf16)o;
        }
    }
}

// ---------------------------------------------------------------------------
// Fused residual-add + LayerNorm. One block (256 thr) per row of 768.
// ---------------------------------------------------------------------------
__global__ __launch_bounds__(256) void ln_kernel(
    const float* __restrict__ y, const float* __restrict__ resid,
    const float* __restrict__ g, const float* __restrict__ bb,
    bf16* __restrict__ out_bf, float* __restrict__ out_f32)
{
    const int row = blockIdx.x;
    const int tid = threadIdx.x;
    __shared__ float sS[4], sQ[4];

    float x[3], s = 0.0f, sq = 0.0f;
#pragma unroll
    for (int j = 0; j < 3; j++) {
        const int c = tid + j * 256;
        const float v = y[(size_t)row * 768 + c] + resid[(size_t)row * 768 + c];
        x[j] = v; s += v; sq += v * v;
    }
#pragma unroll
    for (int off = 32; off; off >>= 1) { s += __shfl_down(s, off); sq += __shfl_down(sq, off); }
    if ((tid & 63) == 0) { sS[tid >> 6] = s; sQ[tid >> 6] = sq; }
    __syncthreads();
    s  = sS[0] + sS[1] + sS[2] + sS[3];
    sq = sQ[0] + sQ[1] + sQ[2] + sQ[3];
    const float mean = s * (1.0f / 768.0f);
    float var = sq * (1.0f / 768.0f) - mean * mean;
    var = fmaxf(var, 0.0f);
    const float rstd = rsqrtf(var + 1e-12f);
#pragma unroll
    for (int j = 0; j < 3; j++) {
        const int c = tid + j * 256;
        const float v = (x[j] - mean) * rstd * g[c] + bb[c];
        out_bf[(size_t)row * 768 + c] = (bf16)v;
        out_f32[(size_t)row * 768 + c] = v;
    }
}

// ---------------------------------------------------------------------------
// Transpose + quantize all 6 fp32 weight matrices of one layer into bf16 wT.
// ---------------------------------------------------------------------------
__global__ __launch_bounds__(256) void transpose_kernel(
    const float* __restrict__ Wq, const float* __restrict__ Wk, const float* __restrict__ Wv,
    const float* __restrict__ Wao, const float* __restrict__ Wi, const float* __restrict__ Wo,
    bf16* __restrict__ wT)
{
    __shared__ bf16 tile[64 * 68];
    int id = blockIdx.x;
    const float* src; bf16* dst; int Kd, Nd;
    if (id < 576) {
        const int w = id / 144; id -= w * 144;
        Kd = 768; Nd = 768;
        src = (w == 0) ? Wq : (w == 1) ? Wk : (w == 2) ? Wv : Wao;
        dst = wT + (size_t)w * 589824;
    } else if (id < 1152) {
        id -= 576; Kd = 768; Nd = 3072; src = Wi; dst = wT + 2359296;
    } else {
        id -= 1152; Kd = 3072; Nd = 768; src = Wo; dst = wT + 4718592;
    }
    const int tn = Nd >> 6;
    const int tr = id / tn, tc = id - tr * tn;
    const int r0 = tr * 64, c0 = tc * 64;
    const int tid = threadIdx.x;

#pragma unroll
    for (int i = 0; i < 4; i++) {
        const int idx = i * 256 + tid;
        const int r = idx >> 4, c4 = (idx & 15) * 4;
        const float4 f = *(const float4*)(src + (size_t)(r0 + r) * Nd + c0 + c4);
        alignas(8) bf16 q[4] = {(bf16)f.x, (bf16)f.y, (bf16)f.z, (bf16)f.w};
        *(ushort4*)(tile + r * 68 + c4) = *(ushort4*)q;
    }
    __syncthreads();
#pragma unroll
    for (int i = 0; i < 4; i++) {
        const int idx = i * 256 + tid;
        const int n = idx >> 4, kc = (idx & 15) * 4;
        alignas(8) bf16 tmp[4];
#pragma unroll
        for (int e = 0; e < 4; e++) tmp[e] = tile[(kc + e) * 68 + n];
        *(ushort4*)(dst + (size_t)(c0 + n) * Kd + r0 + kc) = *(ushort4*)tmp;
    }
}

__global__ __launch_bounds__(256) void convert_kernel(
    const float* __restrict__ in, bf16* __restrict__ out, int n)
{
    const int i = blockIdx.x * 256 + threadIdx.x;
    if (i < n) out[i] = (bf16)in[i];
}

// ---------------------------------------------------------------------------
extern "C" void kernel_launch(void* const* d_in, const int* in_sizes, int n_in,
                              void* d_out, int out_size, void* d_ws, size_t ws_size,
                              hipStream_t stream)
{
    const float* hidden = (const float*)d_in[0];
    const float* mask   = (const float*)d_in[1];
    const float* Wq  = (const float*)d_in[2];  const float* bq  = (const float*)d_in[3];
    const float* Wk  = (const float*)d_in[4];  const float* bk  = (const float*)d_in[5];
    const float* Wv  = (const float*)d_in[6];  const float* bv  = (const float*)d_in[7];
    const float* Wao = (const float*)d_in[8];  const float* bao = (const float*)d_in[9];
    const float* g1  = (const float*)d_in[10]; const float* be1 = (const float*)d_in[11];
    const float* Wi  = (const float*)d_in[12]; const float* bi  = (const float*)d_in[13];
    const float* Wo  = (const float*)d_in[14]; const float* bo  = (const float*)d_in[15];
    const float* g2  = (const float*)d_in[16]; const float* be2 = (const float*)d_in[17];

    // workspace layout (~96 MB):
    char* ws = (char*)d_ws;
    bf16*  wT    = (bf16*)(ws);                    // [0, 14155776)
    bf16*  qkv   = (bf16*)(ws + 14155776);         // [14155776, 33030144)
    bf16*  ctx   = (bf16*)(ws + 33030144);         // [33030144, 39321600)
    bf16*  ffh   = (bf16*)(ws + 14155776);         // aliases qkv+ctx (dead by FF1)
    float* g32   = (float*)(ws + 39321600);        // [39321600, 51904512)
    float* xf    = (float*)(ws + 51904512);        // [51904512, 64487424)
    bf16*  attnb = (bf16*)(ws + 64487424);         // [64487424, 70778880)
    float* attnf = (float*)(ws + 70778880);        // [70778880, 83361792)
    bf16*  xb    = (bf16*)(ws + 83361792);         // [83361792, 89653248)
    bf16*  vT    = (bf16*)(ws + 89653248);         // [89653248, 95944704)

    convert_kernel<<<12288, 256, 0, stream>>>(hidden, xb, 3145728);

    for (int l = 0; l < 12; l++) {
        transpose_kernel<<<1728, 256, 0, stream>>>(
            Wq + (size_t)l * 589824, Wk + (size_t)l * 589824, Wv + (size_t)l * 589824,
            Wao + (size_t)l * 589824, Wi + (size_t)l * 2359296, Wo + (size_t)l * 2359296, wT);

        gemm_kernel<0><<<dim3(18, 32), 256, 0, stream>>>(
            xb, wT, bq + l * 768, bk + l * 768, bv + l * 768, 768, 1536,
            qkv, 4096, 2304, 768);

        vtrans_kernel<<<dim3(4, 96), 256, 0, stream>>>(qkv, vT);

        attn_kernel<<<dim3(16, 12, 8), 256, 0, stream>>>(qkv, vT, mask, ctx);

        gemm_kernel<1><<<dim3(6, 32), 256, 0, stream>>>(
            ctx, wT + 1769472, bao + l * 768, bao + l * 768, bao + l * 768, 768, 768,
            g32, 4096, 768, 768);

        const float* resid1 = (l == 0) ? hidden : xf;
        ln_kernel<<<4096, 256, 0, stream>>>(g32, resid1, g1 + l * 768, be1 + l * 768, attnb, attnf);

        gemm_kernel<2><<<dim3(24, 32), 256, 0, stream>>>(
            attnb, wT + 2359296, bi + l * 3072, bi + l * 3072, bi + l * 3072, 3072, 3072,
            ffh, 4096, 3072, 768);

        gemm_kernel<1><<<dim3(6, 32), 256, 0, stream>>>(
            ffh, wT + 4718592, bo + l * 768, bo + l * 768, bo + l * 768, 768, 768,
            g32, 4096, 768, 3072);

        float* f32dst = (l == 11) ? (float*)d_out : xf;
        ln_kernel<<<4096, 256, 0, stream>>>(g32, attnf, g2 + l * 768, be2 + l * 768, xb, f32dst);
    }
}